// Round 17
// baseline (358.029 us; speedup 1.0000x reference)
//
#include <hip/hip_runtime.h>
#include <math.h>

#define BATCH 8
#define NN    2048
#define FIN   128
#define FH    256
#define KP1   1639   // ceil(0.8*2048)
#define KP2   820    // ceil(0.5*1639)
#define CAP   64

// ---- init: cnt1=0, inv=-1; block 0 computes ||p1||,||p2|| (fp64) ---------
__global__ __launch_bounds__(256) void init_all(int* __restrict__ cnt,
                                                int* __restrict__ inv,
                                                const float* __restrict__ p1,
                                                const float* __restrict__ p2,
                                                double* __restrict__ norms) {
  int t = blockIdx.x * 256 + threadIdx.x;
  if (t < BATCH * NN) { cnt[t] = 0; inv[t] = -1; }
  if (blockIdx.x == 0) {
    __shared__ double red[256];
    int f = threadIdx.x;
    double v = (double)p1[f];
    red[f] = v * v;
    __syncthreads();
    for (int s = 128; s > 0; s >>= 1) { if (f < s) red[f] += red[f + s]; __syncthreads(); }
    if (f == 0) norms[0] = sqrt(red[0]);
    __syncthreads();
    v = (double)p2[f];
    red[f] = v * v;
    __syncthreads();
    for (int s = 128; s > 0; s >>= 1) { if (f < s) red[f] += red[f + s]; __syncthreads(); }
    if (f == 0) norms[1] = sqrt(red[0]);
  }
}

// ---------------- build CSC of A (one coalesced pass, float4) -------------
__global__ void build_csc1(const float* __restrict__ A, int* __restrict__ cnt,
                           int* __restrict__ idx, float* __restrict__ val) {
  const int total = BATCH * NN * (NN / 4);
  for (int t = blockIdx.x * blockDim.x + threadIdx.x; t < total;
       t += gridDim.x * blockDim.x) {
    float4 v4 = reinterpret_cast<const float4*>(A)[t];
    int b = t / (NN * NN / 4);
    int rem = t % (NN * NN / 4);
    int j = rem / (NN / 4);
    int i0 = (rem % (NN / 4)) * 4;
    float vv[4] = {v4.x, v4.y, v4.z, v4.w};
#pragma unroll
    for (int c = 0; c < 4; ++c) {
      float v = vv[c];
      if (v != 0.0f) {
        int col = b * NN + i0 + c;
        int p = atomicAdd(&cnt[col], 1);
        if (p < CAP) { idx[col * CAP + p] = j; val[col * CAP + p] = v; }
      }
    }
  }
}

// ------ canonicalize: one WAVE per column, in-register bitonic sort -------
__global__ __launch_bounds__(256) void canon_cols(int* __restrict__ cnt,
                                                  int* __restrict__ idx,
                                                  float* __restrict__ val,
                                                  double* __restrict__ dinv) {
  int wid = (blockIdx.x * blockDim.x + threadIdx.x) >> 6;
  int lane = threadIdx.x & 63;
  if (wid >= BATCH * NN) return;
  int c = cnt[wid]; if (c > CAP) c = CAP;
  if (lane == 0) cnt[wid] = c;
  int key = 0x7fffffff;
  float v = 0.0f;
  if (lane < c) {
    key = idx[(size_t)wid * CAP + lane];
    v = val[(size_t)wid * CAP + lane];
  }
#pragma unroll
  for (int k = 2; k <= 64; k <<= 1) {
#pragma unroll
    for (int j = k >> 1; j > 0; j >>= 1) {
      int pk = __shfl_xor(key, j);
      float pv = __shfl_xor(v, j);
      bool up = ((lane & k) == 0);
      bool takeMin = (((lane & j) == 0) == up);
      bool sw = takeMin ? (pk < key) : (pk > key);
      if (sw) { key = pk; v = pv; }
    }
  }
  if (lane < c) {
    idx[(size_t)wid * CAP + lane] = key;
    val[(size_t)wid * CAP + lane] = v;
  }
  double dv = (double)v;
#pragma unroll
  for (int off = 32; off > 0; off >>= 1) dv += __shfl_xor(dv, off);
  if (lane == 0) dinv[wid] = 1.0 / sqrt(1.0 + dv);
}

// --- Y = dinv[row]*(Xrow @ W) fp64; 512 thr, 32 rows, 4x4 tile, LDS chunk -
// 1-D grid: bid = rowblk*8 + b  => batch b pinned to XCD b.
// GATHER: Xrow = X[perm[row]] * gvals[row] (fused pool; exact fp64).
template <int KD, typename TX, bool GATHER>
__global__ __launch_bounds__(512) void gemm_y(const TX* __restrict__ X,
                                              const float* __restrict__ W,
                                              const double* __restrict__ dinv,
                                              double* __restrict__ Y, int rows,
                                              const int* __restrict__ perm,
                                              const double* __restrict__ gvals) {
  const int KC = 32;
  int bid = blockIdx.x;
  int b = bid & 7;
  int r0 = (bid >> 3) * 32;
  int t = threadIdx.x;
  int fq = (t & 63) * 4;
  int rg = (t >> 6) * 4;
  __shared__ TX xs[32][KC];
  __shared__ float wsh[KC][FH];
  const TX* Xb = X + (size_t)b * NN * KD;
  double acc[4][4];
#pragma unroll
  for (int r = 0; r < 4; ++r)
#pragma unroll
    for (int c = 0; c < 4; ++c) acc[r][c] = 0.0;

  for (int kc = 0; kc < KD; kc += KC) {
    __syncthreads();
    for (int e = t; e < 32 * KC; e += 512) {
      int r = e >> 5, k = e & 31;
      int row = r0 + r;
      if (GATHER) {
        if (row < rows) {
          int src = perm[b * NN + row];
          double scl = gvals[b * NN + row];
          xs[r][k] = (TX)(X[((size_t)b * NN + src) * KD + kc + k] * scl);
        } else {
          xs[r][k] = (TX)0;
        }
      } else {
        xs[r][k] = (row < rows) ? Xb[(size_t)row * KD + kc + k] : (TX)0;
      }
    }
    for (int e = t; e < KC * FH / 4; e += 512) {
      int k = e >> 6;
      int f = (e << 2) & 255;
      *reinterpret_cast<float4*>(&wsh[k][f]) =
          *reinterpret_cast<const float4*>(&W[(size_t)(kc + k) * FH + f]);
    }
    __syncthreads();
#pragma unroll 2
    for (int k = 0; k < KC; k += 2) {
      float4 waf = *reinterpret_cast<const float4*>(&wsh[k][fq]);
      float4 wbf = *reinterpret_cast<const float4*>(&wsh[k + 1][fq]);
      double wa0 = (double)waf.x, wa1 = (double)waf.y;
      double wa2 = (double)waf.z, wa3 = (double)waf.w;
      double wb0 = (double)wbf.x, wb1 = (double)wbf.y;
      double wb2 = (double)wbf.z, wb3 = (double)wbf.w;
#pragma unroll
      for (int r = 0; r < 4; ++r) {
        double x0 = (double)xs[rg + r][k];
        double x1 = (double)xs[rg + r][k + 1];
        acc[r][0] = fma(x1, wb0, fma(x0, wa0, acc[r][0]));
        acc[r][1] = fma(x1, wb1, fma(x0, wa1, acc[r][1]));
        acc[r][2] = fma(x1, wb2, fma(x0, wa2, acc[r][2]));
        acc[r][3] = fma(x1, wb3, fma(x0, wa3, acc[r][3]));
      }
    }
  }
#pragma unroll
  for (int r = 0; r < 4; ++r) {
    int row = r0 + rg + r;
    if (row < rows) {
      double d = dinv[b * NN + row];
      double* o = Y + ((size_t)b * NN + row) * FH + fq;
      o[0] = d * acc[r][0];
      o[1] = d * acc[r][1];
      o[2] = d * acc[r][2];
      o[3] = d * acc[r][3];
    }
  }
}

// ---- h = relu(dinv*(self + sum nz) + bias) fp64; dot = h . p fp64 --------
// 1-D grid: blockIdx.x = i*8 + b => batch b pinned to XCD b.
__global__ __launch_bounds__(FH) void aggregate(
    const double* __restrict__ Y, const int* __restrict__ cnt,
    const int* __restrict__ idx, const float* __restrict__ val,
    const double* __restrict__ dinv, const float* __restrict__ bias,
    const float* __restrict__ p, double* __restrict__ H, double* __restrict__ dot) {
  int b = blockIdx.x & 7, i = blockIdx.x >> 3, f = threadIdx.x;
  int col = b * NN + i;
  const int* ji = idx + (size_t)col * CAP;
  const float* jv = val + (size_t)col * CAP;
  const double* Yb = Y + (size_t)b * NN * FH;
  double acc = Y[(size_t)col * FH + f];  // self loop: dinv_i * xW_i
  int c = cnt[col];
  int a = 0;
  for (; a + 8 <= c; a += 8) {
    double tt[8];
    double vv[8];
#pragma unroll
    for (int u = 0; u < 8; ++u) {
      vv[u] = (double)jv[a + u];
      tt[u] = Yb[(size_t)ji[a + u] * FH + f];
    }
#pragma unroll
    for (int u = 0; u < 8; ++u) acc += vv[u] * tt[u];
  }
  for (; a < c; ++a) {
    acc += (double)jv[a] * Yb[(size_t)ji[a] * FH + f];
  }
  double h = fmax(dinv[col] * acc + (double)bias[f], 0.0);
  H[(size_t)col * FH + f] = h;
  double pd = h * (double)p[f];
#pragma unroll
  for (int off = 32; off > 0; off >>= 1) pd += __shfl_xor(pd, off);
  __shared__ double red[4];
  if ((f & 63) == 0) red[f >> 6] = pd;
  __syncthreads();
  if (f == 0) dot[col] = (red[0] + red[1]) + (red[2] + red[3]);
}

// ---- top-k by O(N^2) rank enumeration (exact, stable: desc key, asc idx) -
// rank_e = #{j : dot_j > dot_e or (dot_j == dot_e and j < e)} — strict total
// order => ranks are a permutation; rank<k writes perm/vals/inv. Monotone
// tanh/nrm => ranking by raw fp64 dot is exactly the stable desc-sort.
__global__ __launch_bounds__(256) void topk_rank(
    const double* __restrict__ dot, const double* __restrict__ norms, int which,
    int valid, int kk, int* __restrict__ perm, double* __restrict__ vals,
    int* __restrict__ inv) {
  __shared__ double kd[NN];
  int b = blockIdx.y, t = threadIdx.x;
  for (int e = t; e < valid; e += 256) kd[e] = dot[b * NN + e];
  __syncthreads();
  int e = blockIdx.x * 256 + t;
  if (e >= valid) return;
  double de = kd[e];
  int rank = 0;
  int j = 0;
  for (; j + 4 <= valid; j += 4) {
    double k0 = kd[j], k1 = kd[j + 1], k2 = kd[j + 2], k3 = kd[j + 3];
    rank += (k0 > de) || (k0 == de && (j + 0) < e);
    rank += (k1 > de) || (k1 == de && (j + 1) < e);
    rank += (k2 > de) || (k2 == de && (j + 2) < e);
    rank += (k3 > de) || (k3 == de && (j + 3) < e);
  }
  for (; j < valid; ++j) rank += (kd[j] > de) || (kd[j] == de && j < e);
  if (rank < kk) {
    perm[b * NN + rank] = e;
    vals[b * NN + rank] = tanh(de / norms[which]);
    inv[b * NN + e] = rank;
  }
}

// ------ CSC of A1 = A[perm][:,perm]: one WAVE per column, ballot-compact --
__global__ __launch_bounds__(256) void build_csc2(
    const int* __restrict__ cnt1, const int* __restrict__ idx1,
    const float* __restrict__ val1, const int* __restrict__ perm,
    const int* __restrict__ inv, int* __restrict__ cnt2, int* __restrict__ idx2,
    float* __restrict__ val2, double* __restrict__ dinv2) {
  int wid = (blockIdx.x * blockDim.x + threadIdx.x) >> 6;
  int lane = threadIdx.x & 63;
  if (wid >= BATCH * KP1) return;
  int b = wid / KP1, ri = wid % KP1;
  int colA = b * NN + perm[b * NN + ri];
  int c = cnt1[colA];
  int rj = -1;
  float v = 0.0f;
  if (lane < c) {
    int j = idx1[(size_t)colA * CAP + lane];
    v = val1[(size_t)colA * CAP + lane];
    rj = inv[b * NN + j];
  }
  bool keep = (lane < c) && (rj >= 0);
  unsigned long long mask = __ballot(keep);
  int pos = __popcll(mask & ((1ull << lane) - 1ull));
  int colB = b * NN + ri;
  if (keep) {
    idx2[(size_t)colB * CAP + pos] = rj;
    val2[(size_t)colB * CAP + pos] = v;
  }
  if (lane == 0) cnt2[colB] = (int)__popcll(mask);
  double dv = keep ? (double)v : 0.0;
#pragma unroll
  for (int off = 32; off > 0; off >>= 1) dv += __shfl_xor(dv, off);
  if (lane == 0) dinv2[colB] = 1.0 / sqrt(1.0 + dv);
}

// -------- final scatter: rows [0,KP2) = h2[perm2]*vals2, rest zeros -------
__global__ __launch_bounds__(FH) void final_kernel(
    const double* __restrict__ H2, const int* __restrict__ perm2,
    const double* __restrict__ vals2, float* __restrict__ out) {
  int b = blockIdx.x & 7, r = blockIdx.x >> 3, f = threadIdx.x;
  float o = 0.0f;
  if (r < KP2) {
    int rr = perm2[b * NN + r];
    o = (float)(H2[((size_t)b * NN + rr) * FH + f] * vals2[b * NN + r]);
  }
  out[((size_t)b * NN + r) * FH + f] = o;
}

extern "C" void kernel_launch(void* const* d_in, const int* in_sizes, int n_in,
                              void* d_out, int out_size, void* d_ws, size_t ws_size,
                              hipStream_t stream) {
  const float* x  = (const float*)d_in[0];
  const float* A  = (const float*)d_in[1];
  const float* W1 = (const float*)d_in[2];
  const float* b1 = (const float*)d_in[3];
  const float* p1 = (const float*)d_in[4];
  const float* W2 = (const float*)d_in[5];
  const float* b2 = (const float*)d_in[6];
  const float* p2 = (const float*)d_in[7];
  float* out = (float*)d_out;

  char* ws = (char*)d_ws;
  size_t off = 0;
  auto alloc = [&](size_t bytes) {
    void* p = ws + off;
    off += (bytes + 255) & ~(size_t)255;
    return p;
  };
  double* dot   = (double*)alloc((size_t)BATCH * NN * 8);
  double* y     = (double*)alloc((size_t)BATCH * NN * FH * 8);
  double* h     = (double*)alloc((size_t)BATCH * NN * FH * 8);
  double* dinv1 = (double*)alloc((size_t)BATCH * NN * 8);
  double* dinv2 = (double*)alloc((size_t)BATCH * NN * 8);
  int*   cnt1  = (int*)alloc((size_t)BATCH * NN * 4);
  int*   idx1  = (int*)alloc((size_t)BATCH * NN * CAP * 4);
  float* val1  = (float*)alloc((size_t)BATCH * NN * CAP * 4);
  int*   cnt2  = (int*)alloc((size_t)BATCH * NN * 4);
  int*   idx2  = (int*)alloc((size_t)BATCH * NN * CAP * 4);
  float* val2  = (float*)alloc((size_t)BATCH * NN * CAP * 4);
  int*   perm1 = (int*)alloc((size_t)BATCH * NN * 4);
  double* vals1 = (double*)alloc((size_t)BATCH * NN * 8);
  int*   perm2 = (int*)alloc((size_t)BATCH * NN * 4);
  double* vals2 = (double*)alloc((size_t)BATCH * NN * 8);
  int*   inv   = (int*)alloc((size_t)BATCH * NN * 4);
  double* norms = (double*)alloc(64);

  init_all<<<BATCH * NN / 256, 256, 0, stream>>>(cnt1, inv, p1, p2, norms);
  build_csc1<<<4096, 256, 0, stream>>>(A, cnt1, idx1, val1);
  canon_cols<<<(BATCH * NN * 64) / 256, 256, 0, stream>>>(cnt1, idx1, val1, dinv1);
  gemm_y<FIN, float, false><<<(NN / 32) * BATCH, 512, 0, stream>>>(
      x, W1, dinv1, y, NN, nullptr, nullptr);
  aggregate<<<NN * BATCH, FH, 0, stream>>>(y, cnt1, idx1, val1, dinv1, b1, p1, h, dot);
  topk_rank<<<dim3(NN / 256, BATCH), 256, 0, stream>>>(dot, norms, 0, NN, KP1,
                                                       perm1, vals1, inv);
  build_csc2<<<(BATCH * KP1 * 64 + 255) / 256, 256, 0, stream>>>(cnt1, idx1, val1, perm1,
                                                                 inv, cnt2, idx2, val2, dinv2);
  gemm_y<FH, double, true><<<((KP1 + 31) / 32) * BATCH, 512, 0, stream>>>(
      h, W2, dinv2, y, KP1, perm1, vals1);
  aggregate<<<KP1 * BATCH, FH, 0, stream>>>(y, cnt2, idx2, val2, dinv2, b2, p2, h, dot);
  topk_rank<<<dim3((KP1 + 255) / 256, BATCH), 256, 0, stream>>>(dot, norms, 1, KP1, KP2,
                                                                perm2, vals2, inv);
  final_kernel<<<NN * BATCH, FH, 0, stream>>>(h, perm2, vals2, out);
}

// Round 18
// 284.322 us; speedup vs baseline: 1.2592x; 1.2592x over previous
//
#include <hip/hip_runtime.h>
#include <math.h>

#define BATCH 8
#define NN    2048
#define FIN   128
#define FH    256
#define KP1   1639   // ceil(0.8*2048)
#define KP2   820    // ceil(0.5*1639)
#define CAP   64

// ---- init: cnt1=0, inv=-1; block 0 computes ||p1||,||p2|| (fp64) ---------
__global__ __launch_bounds__(256) void init_all(int* __restrict__ cnt,
                                                int* __restrict__ inv,
                                                const float* __restrict__ p1,
                                                const float* __restrict__ p2,
                                                double* __restrict__ norms) {
  int t = blockIdx.x * 256 + threadIdx.x;
  if (t < BATCH * NN) { cnt[t] = 0; inv[t] = -1; }
  if (blockIdx.x == 0) {
    __shared__ double red[256];
    int f = threadIdx.x;
    double v = (double)p1[f];
    red[f] = v * v;
    __syncthreads();
    for (int s = 128; s > 0; s >>= 1) { if (f < s) red[f] += red[f + s]; __syncthreads(); }
    if (f == 0) norms[0] = sqrt(red[0]);
    __syncthreads();
    v = (double)p2[f];
    red[f] = v * v;
    __syncthreads();
    for (int s = 128; s > 0; s >>= 1) { if (f < s) red[f] += red[f + s]; __syncthreads(); }
    if (f == 0) norms[1] = sqrt(red[0]);
  }
}

// ---------------- build CSC of A (one coalesced pass, float4) -------------
__global__ void build_csc1(const float* __restrict__ A, int* __restrict__ cnt,
                           int* __restrict__ idx, float* __restrict__ val) {
  const int total = BATCH * NN * (NN / 4);
  for (int t = blockIdx.x * blockDim.x + threadIdx.x; t < total;
       t += gridDim.x * blockDim.x) {
    float4 v4 = reinterpret_cast<const float4*>(A)[t];
    int b = t / (NN * NN / 4);
    int rem = t % (NN * NN / 4);
    int j = rem / (NN / 4);
    int i0 = (rem % (NN / 4)) * 4;
    float vv[4] = {v4.x, v4.y, v4.z, v4.w};
#pragma unroll
    for (int c = 0; c < 4; ++c) {
      float v = vv[c];
      if (v != 0.0f) {
        int col = b * NN + i0 + c;
        int p = atomicAdd(&cnt[col], 1);
        if (p < CAP) { idx[col * CAP + p] = j; val[col * CAP + p] = v; }
      }
    }
  }
}

// ------ canonicalize: one WAVE per column, in-register bitonic sort -------
__global__ __launch_bounds__(256) void canon_cols(int* __restrict__ cnt,
                                                  int* __restrict__ idx,
                                                  float* __restrict__ val,
                                                  double* __restrict__ dinv) {
  int wid = (blockIdx.x * blockDim.x + threadIdx.x) >> 6;
  int lane = threadIdx.x & 63;
  if (wid >= BATCH * NN) return;
  int c = cnt[wid]; if (c > CAP) c = CAP;
  if (lane == 0) cnt[wid] = c;
  int key = 0x7fffffff;
  float v = 0.0f;
  if (lane < c) {
    key = idx[(size_t)wid * CAP + lane];
    v = val[(size_t)wid * CAP + lane];
  }
#pragma unroll
  for (int k = 2; k <= 64; k <<= 1) {
#pragma unroll
    for (int j = k >> 1; j > 0; j >>= 1) {
      int pk = __shfl_xor(key, j);
      float pv = __shfl_xor(v, j);
      bool up = ((lane & k) == 0);
      bool takeMin = (((lane & j) == 0) == up);
      bool sw = takeMin ? (pk < key) : (pk > key);
      if (sw) { key = pk; v = pv; }
    }
  }
  if (lane < c) {
    idx[(size_t)wid * CAP + lane] = key;
    val[(size_t)wid * CAP + lane] = v;
  }
  double dv = (double)v;
#pragma unroll
  for (int off = 32; off > 0; off >>= 1) dv += __shfl_xor(dv, off);
  if (lane == 0) dinv[wid] = 1.0 / sqrt(1.0 + dv);
}

// --- Y = dinv[row]*(Xrow @ W) fp64; 512 thr, 32 rows, 4x4 tile, LDS chunk -
// 1-D grid: bid = rowblk*8 + b  => batch b pinned to XCD b.
// GATHER: Xrow = X[perm[row]] * gvals[row] (fused pool; exact fp64).
template <int KD, typename TX, bool GATHER>
__global__ __launch_bounds__(512) void gemm_y(const TX* __restrict__ X,
                                              const float* __restrict__ W,
                                              const double* __restrict__ dinv,
                                              double* __restrict__ Y, int rows,
                                              const int* __restrict__ perm,
                                              const double* __restrict__ gvals) {
  const int KC = 32;
  int bid = blockIdx.x;
  int b = bid & 7;
  int r0 = (bid >> 3) * 32;
  int t = threadIdx.x;
  int fq = (t & 63) * 4;
  int rg = (t >> 6) * 4;
  __shared__ TX xs[32][KC];
  __shared__ float wsh[KC][FH];
  const TX* Xb = X + (size_t)b * NN * KD;
  double acc[4][4];
#pragma unroll
  for (int r = 0; r < 4; ++r)
#pragma unroll
    for (int c = 0; c < 4; ++c) acc[r][c] = 0.0;

  for (int kc = 0; kc < KD; kc += KC) {
    __syncthreads();
    for (int e = t; e < 32 * KC; e += 512) {
      int r = e >> 5, k = e & 31;
      int row = r0 + r;
      if (GATHER) {
        if (row < rows) {
          int src = perm[b * NN + row];
          double scl = gvals[b * NN + row];
          xs[r][k] = (TX)(X[((size_t)b * NN + src) * KD + kc + k] * scl);
        } else {
          xs[r][k] = (TX)0;
        }
      } else {
        xs[r][k] = (row < rows) ? Xb[(size_t)row * KD + kc + k] : (TX)0;
      }
    }
    for (int e = t; e < KC * FH / 4; e += 512) {
      int k = e >> 6;
      int f = (e << 2) & 255;
      *reinterpret_cast<float4*>(&wsh[k][f]) =
          *reinterpret_cast<const float4*>(&W[(size_t)(kc + k) * FH + f]);
    }
    __syncthreads();
#pragma unroll 2
    for (int k = 0; k < KC; k += 2) {
      float4 waf = *reinterpret_cast<const float4*>(&wsh[k][fq]);
      float4 wbf = *reinterpret_cast<const float4*>(&wsh[k + 1][fq]);
      double wa0 = (double)waf.x, wa1 = (double)waf.y;
      double wa2 = (double)waf.z, wa3 = (double)waf.w;
      double wb0 = (double)wbf.x, wb1 = (double)wbf.y;
      double wb2 = (double)wbf.z, wb3 = (double)wbf.w;
#pragma unroll
      for (int r = 0; r < 4; ++r) {
        double x0 = (double)xs[rg + r][k];
        double x1 = (double)xs[rg + r][k + 1];
        acc[r][0] = fma(x1, wb0, fma(x0, wa0, acc[r][0]));
        acc[r][1] = fma(x1, wb1, fma(x0, wa1, acc[r][1]));
        acc[r][2] = fma(x1, wb2, fma(x0, wa2, acc[r][2]));
        acc[r][3] = fma(x1, wb3, fma(x0, wa3, acc[r][3]));
      }
    }
  }
#pragma unroll
  for (int r = 0; r < 4; ++r) {
    int row = r0 + rg + r;
    if (row < rows) {
      double d = dinv[b * NN + row];
      double* o = Y + ((size_t)b * NN + row) * FH + fq;
      o[0] = d * acc[r][0];
      o[1] = d * acc[r][1];
      o[2] = d * acc[r][2];
      o[3] = d * acc[r][3];
    }
  }
}

// ---- h = relu(dinv*(self + sum nz) + bias) fp64; dot = h . p fp64 --------
// 1-D grid: blockIdx.x = i*8 + b => batch b pinned to XCD b.
__global__ __launch_bounds__(FH) void aggregate(
    const double* __restrict__ Y, const int* __restrict__ cnt,
    const int* __restrict__ idx, const float* __restrict__ val,
    const double* __restrict__ dinv, const float* __restrict__ bias,
    const float* __restrict__ p, double* __restrict__ H, double* __restrict__ dot) {
  int b = blockIdx.x & 7, i = blockIdx.x >> 3, f = threadIdx.x;
  int col = b * NN + i;
  const int* ji = idx + (size_t)col * CAP;
  const float* jv = val + (size_t)col * CAP;
  const double* Yb = Y + (size_t)b * NN * FH;
  double acc = Y[(size_t)col * FH + f];  // self loop: dinv_i * xW_i
  int c = cnt[col];
  int a = 0;
  for (; a + 8 <= c; a += 8) {
    double tt[8];
    double vv[8];
#pragma unroll
    for (int u = 0; u < 8; ++u) {
      vv[u] = (double)jv[a + u];
      tt[u] = Yb[(size_t)ji[a + u] * FH + f];
    }
#pragma unroll
    for (int u = 0; u < 8; ++u) acc += vv[u] * tt[u];
  }
  for (; a < c; ++a) {
    acc += (double)jv[a] * Yb[(size_t)ji[a] * FH + f];
  }
  double h = fmax(dinv[col] * acc + (double)bias[f], 0.0);
  H[(size_t)col * FH + f] = h;
  double pd = h * (double)p[f];
#pragma unroll
  for (int off = 32; off > 0; off >>= 1) pd += __shfl_xor(pd, off);
  __shared__ double red[4];
  if ((f & 63) == 0) red[f >> 6] = pd;
  __syncthreads();
  if (f == 0) dot[col] = (red[0] + red[1]) + (red[2] + red[3]);
}

// ---- top-k rank, WAVE-PARALLEL: one wave per element ---------------------
// rank_e = #{j : dot_j > dot_e or (dot_j == dot_e and j < e)} — strict total
// order => ranks are a permutation; rank<k writes perm/vals/inv (monotone
// tanh/nrm => exactly the stable desc-sort). 64 lanes stride j with
// coalesced independent L2 loads; 6-step shuffle reduce; no LDS, no chain.
__global__ __launch_bounds__(256) void topk_rank(
    const double* __restrict__ dot, const double* __restrict__ norms, int which,
    int valid, int kk, int* __restrict__ perm, double* __restrict__ vals,
    int* __restrict__ inv) {
  int b = blockIdx.y;
  int wave = threadIdx.x >> 6, lane = threadIdx.x & 63;
  int e = blockIdx.x * 4 + wave;
  if (e >= valid) return;
  const double* db = dot + b * NN;
  double de = db[e];
  int cnt = 0;
  int j = lane;
  for (; j + 256 <= valid; j += 256) {
    double k0 = db[j];
    double k1 = db[j + 64];
    double k2 = db[j + 128];
    double k3 = db[j + 192];
    cnt += (k0 > de) || (k0 == de && (j + 0) < e);
    cnt += (k1 > de) || (k1 == de && (j + 64) < e);
    cnt += (k2 > de) || (k2 == de && (j + 128) < e);
    cnt += (k3 > de) || (k3 == de && (j + 192) < e);
  }
  for (; j < valid; j += 64) {
    double kj = db[j];
    cnt += (kj > de) || (kj == de && j < e);
  }
#pragma unroll
  for (int off = 32; off > 0; off >>= 1) cnt += __shfl_xor(cnt, off);
  if (lane == 0 && cnt < kk) {
    perm[b * NN + cnt] = e;
    vals[b * NN + cnt] = tanh(de / norms[which]);
    inv[b * NN + e] = cnt;
  }
}

// ------ CSC of A1 = A[perm][:,perm]: one WAVE per column, ballot-compact --
__global__ __launch_bounds__(256) void build_csc2(
    const int* __restrict__ cnt1, const int* __restrict__ idx1,
    const float* __restrict__ val1, const int* __restrict__ perm,
    const int* __restrict__ inv, int* __restrict__ cnt2, int* __restrict__ idx2,
    float* __restrict__ val2, double* __restrict__ dinv2) {
  int wid = (blockIdx.x * blockDim.x + threadIdx.x) >> 6;
  int lane = threadIdx.x & 63;
  if (wid >= BATCH * KP1) return;
  int b = wid / KP1, ri = wid % KP1;
  int colA = b * NN + perm[b * NN + ri];
  int c = cnt1[colA];
  int rj = -1;
  float v = 0.0f;
  if (lane < c) {
    int j = idx1[(size_t)colA * CAP + lane];
    v = val1[(size_t)colA * CAP + lane];
    rj = inv[b * NN + j];
  }
  bool keep = (lane < c) && (rj >= 0);
  unsigned long long mask = __ballot(keep);
  int pos = __popcll(mask & ((1ull << lane) - 1ull));
  int colB = b * NN + ri;
  if (keep) {
    idx2[(size_t)colB * CAP + pos] = rj;
    val2[(size_t)colB * CAP + pos] = v;
  }
  if (lane == 0) cnt2[colB] = (int)__popcll(mask);
  double dv = keep ? (double)v : 0.0;
#pragma unroll
  for (int off = 32; off > 0; off >>= 1) dv += __shfl_xor(dv, off);
  if (lane == 0) dinv2[colB] = 1.0 / sqrt(1.0 + dv);
}

// -------- final scatter: rows [0,KP2) = h2[perm2]*vals2, rest zeros -------
__global__ __launch_bounds__(FH) void final_kernel(
    const double* __restrict__ H2, const int* __restrict__ perm2,
    const double* __restrict__ vals2, float* __restrict__ out) {
  int b = blockIdx.x & 7, r = blockIdx.x >> 3, f = threadIdx.x;
  float o = 0.0f;
  if (r < KP2) {
    int rr = perm2[b * NN + r];
    o = (float)(H2[((size_t)b * NN + rr) * FH + f] * vals2[b * NN + r]);
  }
  out[((size_t)b * NN + r) * FH + f] = o;
}

extern "C" void kernel_launch(void* const* d_in, const int* in_sizes, int n_in,
                              void* d_out, int out_size, void* d_ws, size_t ws_size,
                              hipStream_t stream) {
  const float* x  = (const float*)d_in[0];
  const float* A  = (const float*)d_in[1];
  const float* W1 = (const float*)d_in[2];
  const float* b1 = (const float*)d_in[3];
  const float* p1 = (const float*)d_in[4];
  const float* W2 = (const float*)d_in[5];
  const float* b2 = (const float*)d_in[6];
  const float* p2 = (const float*)d_in[7];
  float* out = (float*)d_out;

  char* ws = (char*)d_ws;
  size_t off = 0;
  auto alloc = [&](size_t bytes) {
    void* p = ws + off;
    off += (bytes + 255) & ~(size_t)255;
    return p;
  };
  double* dot   = (double*)alloc((size_t)BATCH * NN * 8);
  double* y     = (double*)alloc((size_t)BATCH * NN * FH * 8);
  double* h     = (double*)alloc((size_t)BATCH * NN * FH * 8);
  double* dinv1 = (double*)alloc((size_t)BATCH * NN * 8);
  double* dinv2 = (double*)alloc((size_t)BATCH * NN * 8);
  int*   cnt1  = (int*)alloc((size_t)BATCH * NN * 4);
  int*   idx1  = (int*)alloc((size_t)BATCH * NN * CAP * 4);
  float* val1  = (float*)alloc((size_t)BATCH * NN * CAP * 4);
  int*   cnt2  = (int*)alloc((size_t)BATCH * NN * 4);
  int*   idx2  = (int*)alloc((size_t)BATCH * NN * CAP * 4);
  float* val2  = (float*)alloc((size_t)BATCH * NN * CAP * 4);
  int*   perm1 = (int*)alloc((size_t)BATCH * NN * 4);
  double* vals1 = (double*)alloc((size_t)BATCH * NN * 8);
  int*   perm2 = (int*)alloc((size_t)BATCH * NN * 4);
  double* vals2 = (double*)alloc((size_t)BATCH * NN * 8);
  int*   inv   = (int*)alloc((size_t)BATCH * NN * 4);
  double* norms = (double*)alloc(64);

  init_all<<<BATCH * NN / 256, 256, 0, stream>>>(cnt1, inv, p1, p2, norms);
  build_csc1<<<4096, 256, 0, stream>>>(A, cnt1, idx1, val1);
  canon_cols<<<(BATCH * NN * 64) / 256, 256, 0, stream>>>(cnt1, idx1, val1, dinv1);
  gemm_y<FIN, float, false><<<(NN / 32) * BATCH, 512, 0, stream>>>(
      x, W1, dinv1, y, NN, nullptr, nullptr);
  aggregate<<<NN * BATCH, FH, 0, stream>>>(y, cnt1, idx1, val1, dinv1, b1, p1, h, dot);
  topk_rank<<<dim3(NN / 4, BATCH), 256, 0, stream>>>(dot, norms, 0, NN, KP1,
                                                     perm1, vals1, inv);
  build_csc2<<<(BATCH * KP1 * 64 + 255) / 256, 256, 0, stream>>>(cnt1, idx1, val1, perm1,
                                                                 inv, cnt2, idx2, val2, dinv2);
  gemm_y<FH, double, true><<<((KP1 + 31) / 32) * BATCH, 512, 0, stream>>>(
      h, W2, dinv2, y, KP1, perm1, vals1);
  aggregate<<<KP1 * BATCH, FH, 0, stream>>>(y, cnt2, idx2, val2, dinv2, b2, p2, h, dot);
  topk_rank<<<dim3((KP1 + 3) / 4, BATCH), 256, 0, stream>>>(dot, norms, 1, KP1, KP2,
                                                            perm2, vals2, inv);
  final_kernel<<<NN * BATCH, FH, 0, stream>>>(h, perm2, vals2, out);
}